// Round 10
// baseline (554.187 us; speedup 1.0000x reference)
//
#include <hip/hip_runtime.h>

typedef unsigned short u16;
typedef __bf16 bf16x8 __attribute__((ext_vector_type(8)));
typedef float f32x4 __attribute__((ext_vector_type(4)));

__device__ __forceinline__ float bf2f(u16 u) {
  union { unsigned int i; float f; } v; v.i = ((unsigned int)u) << 16; return v.f;
}
__device__ __forceinline__ u16 f2bf(float f) {
  union { float f; unsigned int i; } v; v.f = f;
  unsigned int i = v.i;
  return (u16)((i + 0x7fffu + ((i >> 16) & 1u)) >> 16);  // RNE
}
__device__ __forceinline__ float ldf(const float* p) { return *p; }
__device__ __forceinline__ float ldf(const u16* p) { return bf2f(*p); }

// exact-GELU via Abramowitz-Stegun 7.1.26 erf (|err| <= 1.5e-7, branchless)
__device__ __forceinline__ float gelu_f(float v) {
  float x = fabsf(v) * 0.70710678118654752f;
  float t = __builtin_amdgcn_rcpf(fmaf(0.3275911f, x, 1.0f));
  float poly = t * fmaf(t, fmaf(t, fmaf(t, fmaf(t, 1.061405429f, -1.453152027f),
                                        1.421413741f), -0.284496736f), 0.254829592f);
  float er = fmaf(-poly, __expf(-x * x), 1.0f);      // erf(|x|)
  er = copysignf(er, v);
  return 0.5f * v * (1.0f + er);
}

// async global->LDS, 16B per lane. LDS dest must be the wave-uniform base
// (HW writes base + lane*16); the GLOBAL source IS per-lane (m173).
__device__ __forceinline__ void load_lds16(const u16* g, u16* l) {
  __builtin_amdgcn_global_load_lds(
      (const __attribute__((address_space(1))) unsigned int*)g,
      (__attribute__((address_space(3))) unsigned int*)l, 16, 0, 0);
}

// ---------------- weight transpose + cast: Wt[n*K+k] = bf16(W[k*N+n]) ----
__global__ void transpose_kernel(const float* __restrict__ W, u16* __restrict__ Wt,
                                 int K, int N) {
  int idx = blockIdx.x * 256 + threadIdx.x;
  if (idx >= K * N) return;
  int k = idx / N, n = idx % N;
  Wt[n * K + k] = f2bf(W[idx]);
}

// fc1 weights: transpose + K-reorder nf*25+p -> p*64+nf (matches ps layout)
__global__ void transpose_fc1_kernel(const float* __restrict__ W, u16* __restrict__ Wt) {
  int idx = blockIdx.x * 256 + threadIdx.x;
  if (idx >= 1600 * 1024) return;
  int k = idx >> 10, n = idx & 1023;      // k = nf*25+p (reference order)
  int nf = k / 25, p = k - nf * 25;
  Wt[n * 1600 + p * 64 + nf] = f2bf(W[idx]);
}

// ---------------- layernorm over C=576, 4 rows/block (1 wave each) -------
template <typename T>
__global__ __launch_bounds__(256) void ln_kernel(const T* __restrict__ x,
                                                 const float* __restrict__ w,
                                                 const float* __restrict__ b,
                                                 u16* __restrict__ out) {
  int wave = threadIdx.x >> 6, lane = threadIdx.x & 63;
  long row = (long)blockIdx.x * 4 + wave;
  const T* xr = x + row * 576;
  float v[9];
  float sum = 0.f;
  #pragma unroll
  for (int i = 0; i < 9; ++i) { v[i] = ldf(&xr[lane + i * 64]); sum += v[i]; }
  #pragma unroll
  for (int off = 32; off; off >>= 1) sum += __shfl_xor(sum, off);
  float mean = sum * (1.0f / 576.0f);
  float var = 0.f;
  #pragma unroll
  for (int i = 0; i < 9; ++i) { float d = v[i] - mean; var += d * d; }
  #pragma unroll
  for (int off = 32; off; off >>= 1) var += __shfl_xor(var, off);
  float rstd = rsqrtf(var * (1.0f / 576.0f) + 1e-5f);
  u16* outr = out + row * 576;
  #pragma unroll
  for (int i = 0; i < 9; ++i) {
    int c = lane + i * 64;
    outr[c] = f2bf((v[i] - mean) * rstd * w[c] + b[c]);
  }
}

// ---------------- phase-2 LN -> pixelshuffled layout ---------------------
// ps[b][R=3*h2+a][C=3*w2+b2][nf] = LN(x1)[b, h2*56+w2, nf*9+a*3+b2]
__global__ __launch_bounds__(256) void ln_ps_kernel(const float* __restrict__ x,
                                                    const float* __restrict__ w,
                                                    const float* __restrict__ b,
                                                    u16* __restrict__ ps) {
  __shared__ u16 sh[4][576];
  int wave = threadIdx.x >> 6, lane = threadIdx.x & 63;
  long row = (long)blockIdx.x * 4 + wave;
  const float* xr = x + row * 576;
  float v[9];
  float sum = 0.f;
  #pragma unroll
  for (int i = 0; i < 9; ++i) { v[i] = xr[lane + i * 64]; sum += v[i]; }
  #pragma unroll
  for (int off = 32; off; off >>= 1) sum += __shfl_xor(sum, off);
  float mean = sum * (1.0f / 576.0f);
  float var = 0.f;
  #pragma unroll
  for (int i = 0; i < 9; ++i) { float d = v[i] - mean; var += d * d; }
  #pragma unroll
  for (int off = 32; off; off >>= 1) var += __shfl_xor(var, off);
  float rstd = rsqrtf(var * (1.0f / 576.0f) + 1e-5f);
  #pragma unroll
  for (int i = 0; i < 9; ++i) {
    int c = lane + i * 64;
    sh[wave][c] = f2bf((v[i] - mean) * rstd * w[c] + b[c]);
  }
  __syncthreads();
  int bb = (int)(row / 3136), ij = (int)(row % 3136);
  int h2 = ij / 56, w2 = ij - h2 * 56;
  #pragma unroll
  for (int a = 0; a < 3; ++a)
    #pragma unroll
    for (int b2 = 0; b2 < 3; ++b2) {
      u16 val = sh[wave][lane * 9 + a * 3 + b2];       // nf = lane
      long off = (((long)bb * 168 + 3 * h2 + a) * 168 + (3 * w2 + b2)) * 64 + lane;
      ps[off] = val;
    }
}

// ---------------- window attention, MFMA version -------------------------
__constant__ int c_di[25] = {0,0,0, 1,1,1, 2,2,2, 3,3,3,3,3,3,3, 4,4,4, 5,5,5, 6,6,6};
__constant__ int c_dj[25] = {0,3,6, 1,3,5, 2,3,4, 0,1,2,3,4,5,6, 2,3,4, 1,3,5, 0,3,6};

__global__ __launch_bounds__(256) void attn_kernel(const u16* __restrict__ qkv,
                                                   const float* __restrict__ rpb,
                                                   u16* __restrict__ obuf) {
  int h = blockIdx.y;            // 0..5
  int wi = blockIdx.x;
  int b = wi >> 6, w = wi & 63, wr = w >> 3, wc = w & 7;
  __shared__ __align__(16) u16 Qs[64 * 104];
  __shared__ __align__(16) u16 Ks[64 * 104];
  __shared__ __align__(16) u16 Vt[96 * 72];
  __shared__ __align__(16) u16 Ps[64 * 72];
  int tid = threadIdx.x;
  int lane = tid & 63, wv = tid >> 6;
  int quad = lane >> 4, l15 = lane & 15;
  const float scale = 0.1020620726159658f;  // 96^-0.5

  long base = ((long)b * 3136 + wr * 7 * 56 + wc * 7) * 1728 + h * 96;

  for (int idx = tid; idx < 588; idx += 256) {
    int t = idx / 12, dq = idx % 12;
    int tr = t / 7, tc = t - tr * 7;
    long roff = base + (tr * 56 + tc) * 1728 + dq * 8;
    *(uint4*)&Qs[t * 104 + dq * 8] = *(const uint4*)(qkv + roff);
    *(uint4*)&Ks[t * 104 + dq * 8] = *(const uint4*)(qkv + roff + 576);
  }
  for (int idx = tid; idx < 96 * 15; idx += 256) {
    int d = idx / 15, t = 49 + idx % 15;
    Vt[d * 72 + t] = 0;
  }
  for (int idx = tid; idx < 768; idx += 256) {
    int dq = idx >> 6, t = idx & 63;
    if (t < 49) {
      int tr = t / 7, tc = t - tr * 7;
      uint4 v = *(const uint4*)(qkv + base + (tr * 56 + tc) * 1728 + 1152 + dq * 8);
      const u16* vv = (const u16*)&v;
      #pragma unroll
      for (int kk = 0; kk < 8; ++kk) Vt[(dq * 8 + kk) * 72 + t] = vv[kk];
    }
  }
  __syncthreads();

  f32x4 accS[4] = {};
  #pragma unroll
  for (int k0 = 0; k0 < 3; ++k0) {
    bf16x8 aq = *(const bf16x8*)&Qs[(wv * 16 + l15) * 104 + k0 * 32 + quad * 8];
    #pragma unroll
    for (int nt = 0; nt < 4; ++nt) {
      bf16x8 bk = *(const bf16x8*)&Ks[(nt * 16 + l15) * 104 + k0 * 32 + quad * 8];
      accS[nt] = __builtin_amdgcn_mfma_f32_16x16x32_bf16(aq, bk, accS[nt], 0, 0, 0);
    }
  }

  #pragma unroll
  for (int r = 0; r < 4; ++r) {
    int rg = wv * 16 + quad * 4 + r;
    int yi = rg / 7, xi = rg - yi * 7;
    float sv[4];
    float mx = -3e38f;
    #pragma unroll
    for (int nt = 0; nt < 4; ++nt) {
      int col = nt * 16 + l15;
      float s = accS[nt][r] * scale;
      if (rg < 49 && col < 49) {
        int yj = col / 7, xj = col - yj * 7;
        s += rpb[((yi - yj + 6) * 13 + (xi - xj + 6)) * 6 + h];
      } else {
        s = -3e38f;
      }
      sv[nt] = s;
      mx = fmaxf(mx, s);
    }
    #pragma unroll
    for (int off = 8; off; off >>= 1) mx = fmaxf(mx, __shfl_xor(mx, off));
    float sum = 0.f;
    #pragma unroll
    for (int nt = 0; nt < 4; ++nt) { sv[nt] = __expf(sv[nt] - mx); sum += sv[nt]; }
    #pragma unroll
    for (int off = 8; off; off >>= 1) sum += __shfl_xor(sum, off);
    float inv = 1.0f / sum;
    u16* psr = Ps + rg * 72;
    #pragma unroll
    for (int nt = 0; nt < 4; ++nt) psr[nt * 16 + l15] = f2bf(sv[nt] * inv);
  }
  __syncthreads();

  f32x4 accO[6] = {};
  #pragma unroll
  for (int k0 = 0; k0 < 2; ++k0) {
    bf16x8 ap = *(const bf16x8*)&Ps[(wv * 16 + l15) * 72 + k0 * 32 + quad * 8];
    #pragma unroll
    for (int nt = 0; nt < 6; ++nt) {
      bf16x8 bv = *(const bf16x8*)&Vt[(nt * 16 + l15) * 72 + k0 * 32 + quad * 8];
      accO[nt] = __builtin_amdgcn_mfma_f32_16x16x32_bf16(ap, bv, accO[nt], 0, 0, 0);
    }
  }
  #pragma unroll
  for (int r = 0; r < 4; ++r) {
    int rg = wv * 16 + quad * 4 + r;
    if (rg < 49) {
      int tr = rg / 7, tc = rg - tr * 7;
      long ooff = ((long)b * 3136 + (wr * 7 + tr) * 56 + wc * 7 + tc) * 576 + h * 96;
      #pragma unroll
      for (int nt = 0; nt < 6; ++nt) obuf[ooff + nt * 16 + l15] = f2bf(accO[nt][r]);
    }
  }
}

// ---------------- generic bf16 MFMA GEMM (qkv / proj / fc2) --------------
// R10: BK=64 (half the barrier/vmcnt events vs BK=32; 32 MFMA per event),
// dbuf 64 KB LDS (2 blocks/CU), depth-1 counted vmcnt(8).
// T2 XOR swizzle (required at 128B row stride, else 16-way bank conflict):
// linear LDS + inverse-permuted GLOBAL source (kcol = ((tid&7)^((tid>>3)&7))*8,
// per-thread constant) + matching XOR on ds_read (chunk = (ks*4+quad)^(l15&7)).
// XCD-chunked bijective swizzle. M%128==0, K%64==0 at all call sites.
// N remainder: B staging row clamped, stores guarded on col < N.
template <int EPI, typename TR, typename TO>
__global__ __launch_bounds__(256) void gemm_kernel(const u16* __restrict__ A,
                                                   const u16* __restrict__ Bt,
                                                   const float* __restrict__ bias,
                                                   const TR* __restrict__ res,
                                                   TO* __restrict__ C,
                                                   int M, int N, int K) {
  __shared__ __align__(16) u16 As[2][128 * 64];
  __shared__ __align__(16) u16 Bs[2][128 * 64];

  int nwg = gridDim.x * gridDim.y;
  int flat = blockIdx.y * gridDim.x + blockIdx.x;
  int q = nwg >> 3, r = nwg & 7;
  int xcd = flat & 7, loc = flat >> 3;
  int newflat = ((xcd < r) ? xcd * (q + 1) : r * (q + 1) + (xcd - r) * q) + loc;
  int nblk = newflat % gridDim.x, mblk = newflat / gridDim.x;
  int n0 = nblk * 128;
  int m0 = mblk * 128;

  int tid = threadIdx.x;
  int lane = tid & 63, wv = tid >> 6;
  int quad = lane >> 4, l15 = lane & 15;
  int wr2 = wv >> 1, wc2 = wv & 1;
  f32x4 acc[4][4] = {};

  // staging: chunk = c*256 + tid (16B) -> LDS row chunk>>3, slot chunk&7.
  // source k-chunk inverse-swizzled so linear DMA + XOR read = conflict-free.
  int swz = ((tid & 7) ^ ((tid >> 3) & 7)) * 8;
  int r0 = tid >> 3;
  const u16 *gAc[4], *gBc[4];
  #pragma unroll
  for (int c = 0; c < 4; ++c) {
    gAc[c] = A + (long)(m0 + c * 32 + r0) * K + swz;
    int rB = n0 + c * 32 + r0; if (rB > N - 1) rB = N - 1;
    gBc[c] = Bt + (long)rB * K + swz;
  }
  int ldsoff = wv * 512;                    // wave-uniform (elements)

  int nt = K >> 6;
  auto stage = [&](int bufi, int t) {
    #pragma unroll
    for (int c = 0; c < 4; ++c) load_lds16(gAc[c] + t * 64, &As[bufi][c * 2048 + ldsoff]);
    #pragma unroll
    for (int c = 0; c < 4; ++c) load_lds16(gBc[c] + t * 64, &Bs[bufi][c * 2048 + ldsoff]);
  };
  auto compute = [&](int cur) {
    #pragma unroll
    for (int ks = 0; ks < 2; ++ks) {
      int cc = ((ks * 4 + quad) ^ (l15 & 7)) * 8;
      bf16x8 a[4], bb[4];
      #pragma unroll
      for (int mi = 0; mi < 4; ++mi)
        a[mi] = *(const bf16x8*)&As[cur][(wr2 * 64 + mi * 16 + l15) * 64 + cc];
      #pragma unroll
      for (int ni = 0; ni < 4; ++ni)
        bb[ni] = *(const bf16x8*)&Bs[cur][(wc2 * 64 + ni * 16 + l15) * 64 + cc];
      #pragma unroll
      for (int mi = 0; mi < 4; ++mi)
        #pragma unroll
        for (int ni = 0; ni < 4; ++ni)
          acc[mi][ni] = __builtin_amdgcn_mfma_f32_16x16x32_bf16(a[mi], bb[ni], acc[mi][ni], 0, 0, 0);
    }
  };

  stage(0, 0);
  for (int t = 0; t < nt - 1; ++t) {
    int cur = t & 1;
    stage(cur ^ 1, t + 1);
    asm volatile("s_waitcnt vmcnt(8)" ::: "memory");
    __builtin_amdgcn_s_barrier();
    compute(cur);
    __builtin_amdgcn_s_barrier();
  }
  asm volatile("s_waitcnt vmcnt(0)" ::: "memory");
  __builtin_amdgcn_s_barrier();
  compute((nt - 1) & 1);

  #pragma unroll
  for (int mi = 0; mi < 4; ++mi)
    #pragma unroll
    for (int ni = 0; ni < 4; ++ni) {
      int col = n0 + wc2 * 64 + ni * 16 + l15;
      if (col < N) {
        float bz = bias[col];
        #pragma unroll
        for (int rr = 0; rr < 4; ++rr) {
          int row = m0 + wr2 * 64 + mi * 16 + quad * 4 + rr;
          float v = acc[mi][ni][rr] + bz;
          if (EPI == 1) v = gelu_f(v);
          if (EPI == 2) v += ldf(&res[(long)row * N + col]);
          long off = (long)row * N + col;
          if (sizeof(TO) == 2) ((u16*)C)[off] = f2bf(v);
          else                 ((float*)C)[off] = v;
        }
      }
    }
}

// ---------------- fc1: fused gather + GEMM + GELU, BK=64 -----------------
// Same BK=64 + T2-swizzle structure as gemm_kernel. With K = p*64+nf,
// BK=64 makes p == t (one mask position per K-tile): one reflect per
// staged row per tile. A rows: 4 calls, row = c*32 + tid>>3.
__global__ __launch_bounds__(256) void fc1_kernel(const u16* __restrict__ ps,
                                                  const u16* __restrict__ Bt,
                                                  const float* __restrict__ bias,
                                                  u16* __restrict__ C) {
  const int N = 1024, K = 1600;
  __shared__ __align__(16) u16 As[2][128 * 64];
  __shared__ __align__(16) u16 Bs[2][128 * 64];
  __shared__ int s_di[25], s_dj[25];
  if (threadIdx.x < 25) {
    s_di[threadIdx.x] = c_di[threadIdx.x];
    s_dj[threadIdx.x] = c_dj[threadIdx.x];
  }

  int nwg = gridDim.x * gridDim.y;          // 1568, %8 == 0
  int flat = blockIdx.y * gridDim.x + blockIdx.x;
  int q = nwg >> 3;
  int xcd = flat & 7, loc = flat >> 3;
  int newflat = xcd * q + loc;
  int nblk = newflat % gridDim.x, mblk = newflat / gridDim.x;
  int n0 = nblk * 128;
  int m0 = mblk * 128;

  int tid = threadIdx.x;
  int lane = tid & 63, wv = tid >> 6;
  int quad = lane >> 4, l15 = lane & 15;
  int wr2 = wv >> 1, wc2 = wv & 1;
  f32x4 acc[4][4] = {};

  int swz = ((tid & 7) ^ ((tid >> 3) & 7)) * 8;
  int r0 = tid >> 3;
  int uc[4], vc[4];
  const u16 *psb[4], *gBc[4];
  #pragma unroll
  for (int c = 0; c < 4; ++c) {
    int m_ = m0 + c * 32 + r0;
    int b_ = m_ / 3136, ij = m_ % 3136, i_ = ij / 56, j_ = ij - i_ * 56;
    uc[c] = 3 * i_ - 2; vc[c] = 3 * j_ - 2;
    psb[c] = ps + (long)b_ * 1806336 + swz;          // 168*168*64
    gBc[c] = Bt + (long)(n0 + c * 32 + r0) * K + swz;
  }
  int ldsoff = wv * 512;

  __syncthreads();                           // s_di/s_dj ready

  auto stage = [&](int bufi, int t) {
    int dip = s_di[t], djp = s_dj[t];
    #pragma unroll
    for (int c = 0; c < 4; ++c) {
      int R = uc[c] + dip; R = R < 0 ? -R : R; R = R >= 168 ? 334 - R : R;
      int Cc = vc[c] + djp; Cc = Cc < 0 ? -Cc : Cc; Cc = Cc >= 168 ? 334 - Cc : Cc;
      load_lds16(psb[c] + ((R * 168 + Cc) << 6), &As[bufi][c * 2048 + ldsoff]);
    }
    #pragma unroll
    for (int c = 0; c < 4; ++c) load_lds16(gBc[c] + t * 64, &Bs[bufi][c * 2048 + ldsoff]);
  };
  auto compute = [&](int cur) {
    #pragma unroll
    for (int ks = 0; ks < 2; ++ks) {
      int cc = ((ks * 4 + quad) ^ (l15 & 7)) * 8;
      bf16x8 a[4], bb[4];
      #pragma unroll
      for (int mi = 0; mi < 4; ++mi)
        a[mi] = *(const bf16x8*)&As[cur][(wr2 * 64 + mi * 16 + l15) * 64 + cc];
      #pragma unroll
      for (int ni = 0; ni < 4; ++ni)
        bb[ni] = *(const bf16x8*)&Bs[cur][(wc2 * 64 + ni * 16 + l15) * 64 + cc];
      #pragma unroll
      for (int mi = 0; mi < 4; ++mi)
        #pragma unroll
        for (int ni = 0; ni < 4; ++ni)
          acc[mi][ni] = __builtin_amdgcn_mfma_f32_16x16x32_bf16(a[mi], bb[ni], acc[mi][ni], 0, 0, 0);
    }
  };

  const int nt = 25;                         // K/64
  stage(0, 0);
  for (int t = 0; t < nt - 1; ++t) {
    int cur = t & 1;
    stage(cur ^ 1, t + 1);
    asm volatile("s_waitcnt vmcnt(8)" ::: "memory");
    __builtin_amdgcn_s_barrier();
    compute(cur);
    __builtin_amdgcn_s_barrier();
  }
  asm volatile("s_waitcnt vmcnt(0)" ::: "memory");
  __builtin_amdgcn_s_barrier();
  compute((nt - 1) & 1);

  #pragma unroll
  for (int mi = 0; mi < 4; ++mi)
    #pragma unroll
    for (int ni = 0; ni < 4; ++ni) {
      int col = n0 + wc2 * 64 + ni * 16 + l15;
      float bz = bias[col];
      #pragma unroll
      for (int rr = 0; rr < 4; ++rr) {
        int row = m0 + wr2 * 64 + mi * 16 + quad * 4 + rr;
        C[(long)row * N + col] = f2bf(gelu_f(acc[mi][ni][rr] + bz));
      }
    }
}

// ---------------- host launch -------------------------------------------
// Inputs fp32, OUTPUT FP32. ws peak ~87.4 MB.
// x1 lives in d_out f32 (proj writes, ln_ps reads, fc2 res+overwrite in
// place -- idempotent under graph replay). Phase 2 is one full-batch pass.
extern "C" void kernel_launch(void* const* d_in, const int* in_sizes, int n_in,
                              void* d_out, int out_size, void* d_ws, size_t ws_size,
                              hipStream_t stream) {
  const float* x      = (const float*)d_in[0];
  const float* n1w    = (const float*)d_in[1];
  const float* n1b    = (const float*)d_in[2];
  const float* qkv_w  = (const float*)d_in[3];
  const float* qkv_b  = (const float*)d_in[4];
  const float* rpb    = (const float*)d_in[5];
  const float* proj_w = (const float*)d_in[6];
  const float* proj_b = (const float*)d_in[7];
  const float* n2w    = (const float*)d_in[8];
  const float* n2b    = (const float*)d_in[9];
  const float* fc1_w  = (const float*)d_in[10];
  const float* fc1_b  = (const float*)d_in[11];
  const float* fc2_w  = (const float*)d_in[12];
  const float* fc2_b  = (const float*)d_in[13];

  char* ws = (char*)d_ws;
  u16* wt_qkv  = (u16*)(ws + 0);           // 1728x576
  u16* wt_proj = (u16*)(ws + 1990656);     // 576x576
  u16* wt_fc1  = (u16*)(ws + 2654208);     // 1024x1600 (K = p*64+nf order)
  u16* wt_fc2  = (u16*)(ws + 5931008);     // 576x1024
  char* qkvpool = ws + 7110656;            // 43,352,064 B (ph1 qkvb, half)
  char* lnpool  = ws + 50462720;           // 14,450,688 B (ph1 lnb, half)
  u16* ln2ps = (u16*)(ws + 7110656);       // 8x168x168x64 bf16 = 28,901,376 B
  u16* hb    = (u16*)(ws + 36012032);      // 25088x1024 bf16 -> end 87,392,256
  float* x1 = (float*)d_out;               // 25088x576 f32

  transpose_kernel<<<3888, 256, 0, stream>>>(qkv_w, wt_qkv, 576, 1728);
  transpose_kernel<<<1296, 256, 0, stream>>>(proj_w, wt_proj, 576, 576);
  transpose_fc1_kernel<<<6400, 256, 0, stream>>>(fc1_w, wt_fc1);
  transpose_kernel<<<2304, 256, 0, stream>>>(fc2_w, wt_fc2, 1024, 576);

  // ---------- phase 1: two halves of 4 batches (12544 rows each) ----------
  for (int h = 0; h < 2; ++h) {
    const long r0 = (long)h * 12544;
    u16* lnb  = (u16*)lnpool;
    u16* qkvb = (u16*)qkvpool;
    ln_kernel<float><<<3136, 256, 0, stream>>>(x + r0 * 576, n1w, n1b, lnb);
    gemm_kernel<0, float, u16><<<dim3(14, 98), 256, 0, stream>>>(
        lnb, wt_qkv, qkv_b, (const float*)nullptr, qkvb, 12544, 1728, 576);
    attn_kernel<<<dim3(256, 6), 256, 0, stream>>>(qkvb, rpb, lnb);
    gemm_kernel<2, float, float><<<dim3(5, 98), 256, 0, stream>>>(
        lnb, wt_proj, proj_b, x + r0 * 576, x1 + r0 * 576, 12544, 576, 576);
  }

  // ---------- phase 2: full batch, one pass ----------
  ln_ps_kernel<<<6272, 256, 0, stream>>>(x1, n2w, n2b, ln2ps);
  fc1_kernel<<<dim3(8, 196), 256, 0, stream>>>(ln2ps, wt_fc1, fc1_b, hb);
  gemm_kernel<2, float, float><<<dim3(5, 196), 256, 0, stream>>>(
      hb, wt_fc2, fc2_b, x1, x1, 25088, 576, 1024);
}